// Round 4
// baseline (128.063 us; speedup 1.0000x reference)
//
#include <hip/hip_runtime.h>

// GNNDecoder: x_hat = GE[batch] @ node_w.T + node_b ; edge_hat = GE[batch[src]] @ edge_w.T + edge_b
// Structure: per-graph projections P=[B,FN], Q=[B,FE] (tiny GEMM), then outputs are
// pure row-gathers (memory-bound, 512MB nt-stores).
// R4: revert R3's barrier-chunked scatter (syncthreads drains vmcnt -> stalls).
//  - scatter: R2 grid-stride skeleton, node+edge PAIRED per iteration (balance, 2 chains)
//  - eg[] precomputed (edge chain depth 3 -> 2, clamps out of hot loop)
//  - proj: weights staged per-block into LDS transposed (coalesced global loads,
//    conflict-free swT[k][t] lane-consecutive reads) instead of 64-line scattered loads.

#define H   256
#define FN  128
#define FE  64
#define GPB 8    // graphs per proj block
#define KC  64   // k-chunk for weight staging

typedef float f4 __attribute__((ext_vector_type(4)));

__global__ __launch_bounds__(192) void proj_kernel(
    const float* __restrict__ ge,      // [B, H]
    const float* __restrict__ node_w,  // [FN, H]
    const float* __restrict__ node_b,  // [FN]
    const float* __restrict__ edge_w,  // [FE, H]
    const float* __restrict__ edge_b,  // [FE]
    float* __restrict__ P,             // [B, FN]
    float* __restrict__ Q)             // [B, FE]
{
    __shared__ float sge[GPB * H];         // 8 KB, [g][k]
    __shared__ float swT[KC][193];         // 49.4 KB, [kk][f] transposed weight chunk
    const int t  = threadIdx.x;            // 0..191: feature id (0..127 node, 128..191 edge)
    const int g0 = blockIdx.x * GPB;

    // Stage GE rows (8 KB) coalesced.
    const float4* ge4  = reinterpret_cast<const float4*>(ge + (size_t)g0 * H);
    float4*       sge4 = reinterpret_cast<float4*>(sge);
    for (int i = t; i < GPB * H / 4; i += 192) sge4[i] = ge4[i];

    float acc[GPB];
    #pragma unroll
    for (int g = 0; g < GPB; ++g) acc[g] = 0.f;

    for (int k0 = 0; k0 < H; k0 += KC) {
        __syncthreads();   // protects swT reuse (and sge on first iter)
        // Stage weight cols [k0,k0+KC) for all 192 features, transposed into swT.
        // flat idx over 192 features x 16 f4-segments; consecutive lanes -> consecutive
        // segments of the same row => 4 global transactions per wave-load.
        #pragma unroll
        for (int j = 0; j < 16; ++j) {
            const int idx = t + j * 192;       // 0..3071
            const int f   = idx >> 4;          // 0..191
            const int seg = idx & 15;          // 0..15
            const float* wrow = (f < FN) ? (node_w + (size_t)f * H)
                                         : (edge_w + (size_t)(f - FN) * H);
            const float4 wv = *reinterpret_cast<const float4*>(wrow + k0 + seg * 4);
            swT[seg * 4 + 0][f] = wv.x;
            swT[seg * 4 + 1][f] = wv.y;
            swT[seg * 4 + 2][f] = wv.z;
            swT[seg * 4 + 3][f] = wv.w;
        }
        __syncthreads();
        // Compute: swT[kk][t] is lane-consecutive (conflict-free); sge reads broadcast.
        #pragma unroll 4
        for (int kk = 0; kk < KC; kk += 4) {
            const float w0 = swT[kk + 0][t];
            const float w1 = swT[kk + 1][t];
            const float w2 = swT[kk + 2][t];
            const float w3 = swT[kk + 3][t];
            #pragma unroll
            for (int g = 0; g < GPB; ++g) {
                const float* s = sge + g * H + k0 + kk;
                acc[g] += w0 * s[0] + w1 * s[1] + w2 * s[2] + w3 * s[3];
            }
        }
    }

    const float bias = (t < FN) ? node_b[t] : edge_b[t - FN];
    #pragma unroll
    for (int g = 0; g < GPB; ++g) {
        const float v = acc[g] + bias;
        if (t < FN) P[(size_t)(g0 + g) * FN + t]        = v;
        else        Q[(size_t)(g0 + g) * FE + (t - FN)] = v;
    }
}

// eg[e] = batch[src[e]] (clamped) — makes the edge scatter chain identical to node.
__global__ __launch_bounds__(256) void eg_kernel(
    const int* __restrict__ src, const int* __restrict__ batch,
    int* __restrict__ eg, int E, int Nm1, int Bm1)
{
    const int stride = gridDim.x * 256;
    for (int i = blockIdx.x * 256 + threadIdx.x; i < E; i += stride) {
        int s = src[i];
        s = min(max(s, 0), Nm1);
        eg[i] = batch[s] & Bm1;
    }
}

// Paired scatter: each iteration emits one node-f4 and one edge-f4 (n4 == e4 here).
// Barrier-free grid-stride; two independent 2-deep chains per iteration; nt stores.
__global__ __launch_bounds__(256) void scatter_fused(
    const int* __restrict__ batch,     // [N]
    const int* __restrict__ eg,        // [E]
    const f4* __restrict__ P4,         // [B*32]
    const f4* __restrict__ Q4,         // [B*16]
    f4* __restrict__ xout,             // [N*32]
    f4* __restrict__ eout,             // [E*16]
    int n4, int e4, int Bm1)
{
    const int stride = gridDim.x * blockDim.x;
    const int maxT = max(n4, e4);
    for (int i = blockIdx.x * blockDim.x + threadIdx.x; i < maxT; i += stride) {
        if (i < n4) {
            const int r = i >> 5, c = i & 31;
            const int g = batch[r] & Bm1;
            __builtin_nontemporal_store(P4[(g << 5) + c], xout + i);
        }
        if (i < e4) {
            const int e = i >> 4, c2 = i & 15;
            const int g2 = eg[e];
            __builtin_nontemporal_store(Q4[(g2 << 4) + c2], eout + i);
        }
    }
}

extern "C" void kernel_launch(void* const* d_in, const int* in_sizes, int n_in,
                              void* d_out, int out_size, void* d_ws, size_t ws_size,
                              hipStream_t stream) {
    const float* ge     = (const float*)d_in[0];
    const int*   batch  = (const int*)  d_in[1];
    const int*   eidx   = (const int*)  d_in[2];
    const float* node_w = (const float*)d_in[3];
    const float* node_b = (const float*)d_in[4];
    const float* edge_w = (const float*)d_in[5];
    const float* edge_b = (const float*)d_in[6];

    const int B = in_sizes[0] / H;   // 4096
    const int N = in_sizes[1];       // 500000
    const int E = in_sizes[2] / 2;   // 1000000

    float* P  = (float*)d_ws;                // [B, FN]  2 MB
    float* Q  = P + (size_t)B * FN;          // [B, FE]  1 MB
    int*   eg = (int*)(Q + (size_t)B * FE);  // [E]      4 MB

    float* x_hat = (float*)d_out;            // [N, FN]
    float* e_hat = x_hat + (size_t)N * FN;   // [E, FE]

    proj_kernel<<<B / GPB, 192, 0, stream>>>(ge, node_w, node_b, edge_w, edge_b, P, Q);
    eg_kernel<<<1024, 256, 0, stream>>>(eidx, batch, eg, E, N - 1, B - 1);

    const int n4 = N * (FN / 4);             // 16,000,000
    const int e4 = E * (FE / 4);             // 16,000,000
    scatter_fused<<<2048, 256, 0, stream>>>(
        batch, eg, (const f4*)P, (const f4*)Q, (f4*)x_hat, (f4*)e_hat,
        n4, e4, B - 1);
}